// Round 6
// baseline (1363.854 us; speedup 1.0000x reference)
//
#include <hip/hip_runtime.h>
#include <hip/hip_cooperative_groups.h>

namespace cg = cooperative_groups;

#define LORA_SCALE 4.0f
#define ATT_SCALE 8.0f
#define NEG_SLOPE 0.2f

typedef __attribute__((ext_vector_type(8))) short bf16x8;
typedef __attribute__((ext_vector_type(4))) float f32x4;
typedef unsigned short ushort_t;
typedef unsigned int uint_t;

__device__ inline ushort_t f2bf(float f) {
    uint_t u = __float_as_uint(f);
    u += 0x7fff + ((u >> 16) & 1);     // RNE
    return (ushort_t)(u >> 16);
}
__device__ inline float bf2f(ushort_t h) {
    return __uint_as_float(((uint_t)h) << 16);
}
__device__ inline void split_bf(float f, ushort_t& h, ushort_t& l) {
    h = f2bf(f);
    l = f2bf(f - bf2f(h));
}

struct MegaP {
    const float *x; const int *ei;
    const float *W0,*A0,*B0,*as0,*ad0,*As0,*Bs0,*Ad0,*Bd0;
    const float *W1,*A1,*B1,*as1,*ad1,*As1,*Bs1,*Ad1,*Bd1;
    ushort_t *whi0,*wlo0,*whi1,*wlo1;
    float *effS0,*effD0,*effS1,*effD1;
    ushort_t *xhi,*xlo,*hbhi,*hblo;
    float *xp,*ssrc,*sdst;
    int *deg,*rowptr,*cursor,*csr_src;
    float *out;
    int N, E_real, E_total;
};

// ---------------- shared phase bodies ----------------

__device__ inline void weights_body(int i, const MegaP& p)
{
    int layer = i >> 16;
    int idx = i & 65535;
    const float* W = layer ? p.W1 : p.W0;
    const float* A = layer ? p.A1 : p.A0;
    const float* B = layer ? p.B1 : p.B0;
    int r = idx >> 8, c = idx & 255;
    float acc = W[idx];
    #pragma unroll
    for (int k = 0; k < 8; k++) acc += LORA_SCALE * B[r * 8 + k] * A[k * 256 + c];
    ushort_t h, l;
    split_bf(acc, h, l);
    if (layer) { p.whi1[idx] = h; p.wlo1[idx] = l; }
    else       { p.whi0[idx] = h; p.wlo0[idx] = l; }
    if (idx < 256) {
        int c2 = idx & 31;
        const float* as_ = layer ? p.as1 : p.as0;
        const float* ad_ = layer ? p.ad1 : p.ad0;
        const float* As = layer ? p.As1 : p.As0;
        const float* Bs = layer ? p.Bs1 : p.Bs0;
        const float* Ad = layer ? p.Ad1 : p.Ad0;
        const float* Bd = layer ? p.Bd1 : p.Bd0;
        float es = as_[idx], ed = ad_[idx];
        #pragma unroll
        for (int k = 0; k < 4; k++) {
            es += ATT_SCALE * Bs[k] * As[k * 32 + c2];
            ed += ATT_SCALE * Bd[k] * Ad[k * 32 + c2];
        }
        if (layer) { p.effS1[idx] = es; p.effD1[idx] = ed; }
        else       { p.effS0[idx] = es; p.effD0[idx] = ed; }
    }
}

__device__ inline void gemm_phase(const ushort_t* __restrict__ Ahi, const ushort_t* __restrict__ Alo,
                                  const ushort_t* __restrict__ Bhi, const ushort_t* __restrict__ Blo,
                                  const float* __restrict__ effS, const float* __restrict__ effD,
                                  float* __restrict__ C, float* __restrict__ ssrc,
                                  float* __restrict__ sdst, int M, int wave, int lane, int NW)
{
    const int K = 256;
    int quad = lane >> 4;
    int l16 = lane & 15;
    int tiles = 4 * ((M + 15) / 16);
    for (int t0 = wave; t0 < tiles; t0 += NW) {
        int n0 = (t0 & 3) * 64;
        int m0 = (t0 >> 2) * 16;
        int mr = m0 + l16; if (mr >= M) mr = M - 1;

        const ushort_t* ah = Ahi + mr * K + quad * 8;
        const ushort_t* al = Alo + mr * K + quad * 8;
        const ushort_t* bh = Bhi + (n0 + l16) * K + quad * 8;
        const ushort_t* bl = Blo + (n0 + l16) * K + quad * 8;

        f32x4 acc[4] = {};
        #pragma unroll
        for (int k0 = 0; k0 < K; k0 += 32) {
            bf16x8 a_hi = *(const bf16x8*)(ah + k0);
            bf16x8 a_lo = *(const bf16x8*)(al + k0);
            #pragma unroll
            for (int t = 0; t < 4; t++) {
                bf16x8 b_hi = *(const bf16x8*)(bh + t * 16 * K + k0);
                bf16x8 b_lo = *(const bf16x8*)(bl + t * 16 * K + k0);
                acc[t] = __builtin_amdgcn_mfma_f32_16x16x32_bf16(a_hi, b_hi, acc[t], 0, 0, 0);
                acc[t] = __builtin_amdgcn_mfma_f32_16x16x32_bf16(a_hi, b_lo, acc[t], 0, 0, 0);
                acc[t] = __builtin_amdgcn_mfma_f32_16x16x32_bf16(a_lo, b_hi, acc[t], 0, 0, 0);
            }
        }
        #pragma unroll
        for (int t = 0; t < 4; t++) {
            #pragma unroll
            for (int r = 0; r < 4; r++) {
                int m = m0 + quad * 4 + r;
                if (m < M) C[m * 256 + n0 + t * 16 + l16] = acc[t][r];
            }
        }
        int h0 = n0 >> 5;
        float vs[2][4], vd[2][4];
        #pragma unroll
        for (int g = 0; g < 2; g++) {
            float e0s = effS[n0 + 32 * g + l16];
            float e1s = effS[n0 + 32 * g + 16 + l16];
            float e0d = effD[n0 + 32 * g + l16];
            float e1d = effD[n0 + 32 * g + 16 + l16];
            #pragma unroll
            for (int r = 0; r < 4; r++) {
                vs[g][r] = acc[2 * g][r] * e0s + acc[2 * g + 1][r] * e1s;
                vd[g][r] = acc[2 * g][r] * e0d + acc[2 * g + 1][r] * e1d;
            }
        }
        #pragma unroll
        for (int m = 1; m <= 8; m <<= 1) {
            #pragma unroll
            for (int g = 0; g < 2; g++)
                #pragma unroll
                for (int r = 0; r < 4; r++) {
                    vs[g][r] += __shfl_xor(vs[g][r], m);
                    vd[g][r] += __shfl_xor(vd[g][r], m);
                }
        }
        if (l16 == 0) {
            #pragma unroll
            for (int g = 0; g < 2; g++)
                #pragma unroll
                for (int r = 0; r < 4; r++) {
                    int m = m0 + quad * 4 + r;
                    if (m < M) {
                        ssrc[m * 8 + h0 + g] = vs[g][r];
                        sdst[m * 8 + h0 + g] = vd[g][r];
                    }
                }
        }
    }
}

__device__ inline void agg_phase(const int* __restrict__ rowptr, const int* __restrict__ csr_src,
                                 const float* __restrict__ xp, const float* __restrict__ ssrc,
                                 const float* __restrict__ sdst, float* __restrict__ out,
                                 ushort_t* __restrict__ ohi, ushort_t* __restrict__ olo,
                                 int N, int mode, int wave, int lane, int NW)
{
    int h = lane >> 3;
    for (int d = wave; d < N; d += NW) {
        float ssrc_h = ssrc[d * 8 + h];
        int begin = rowptr[d], end = rowptr[d + 1];
        int lim = end - 1;

        float den = 0.f, ax = 0.f, ay = 0.f, az = 0.f, aw = 0.f;
        for (int i = begin; i < end; i += 8) {
            int idx[8];
            #pragma unroll
            for (int j = 0; j < 8; j++) {
                int ii = i + j;
                idx[j] = csr_src[ii < end ? ii : lim];
            }
            float t[8];
            #pragma unroll
            for (int j = 0; j < 8; j++) t[j] = sdst[idx[j] * 8 + h];
            float4 v[8];
            #pragma unroll
            for (int j = 0; j < 8; j++) v[j] = *(const float4*)(xp + idx[j] * 256 + lane * 4);
            float w[8];
            #pragma unroll
            for (int j = 0; j < 8; j++) {
                float al = ssrc_h + t[j];
                al = al > 0.f ? al : NEG_SLOPE * al;
                w[j] = (i + j < end) ? __expf(al) : 0.f;
            }
            #pragma unroll
            for (int j = 0; j < 8; j++) {
                den += w[j];
                ax += v[j].x * w[j];
                ay += v[j].y * w[j];
                az += v[j].z * w[j];
                aw += v[j].w * w[j];
            }
        }
        float inv = 1.f / den;
        ax *= inv; ay *= inv; az *= inv; aw *= inv;

        if (mode == 2) {
            #pragma unroll
            for (int m = 8; m <= 32; m <<= 1) {
                ax += __shfl_xor(ax, m);
                ay += __shfl_xor(ay, m);
                az += __shfl_xor(az, m);
                aw += __shfl_xor(aw, m);
            }
            if (lane < 8) {
                float4 r = { ax * 0.125f, ay * 0.125f, az * 0.125f, aw * 0.125f };
                *(float4*)(out + d * 32 + lane * 4) = r;
            }
        } else {
            ax = ax > 0.f ? ax : (__expf(ax) - 1.f);
            ay = ay > 0.f ? ay : (__expf(ay) - 1.f);
            az = az > 0.f ? az : (__expf(az) - 1.f);
            aw = aw > 0.f ? aw : (__expf(aw) - 1.f);
            ushort4 hs, ls;
            split_bf(ax, hs.x, ls.x);
            split_bf(ay, hs.y, ls.y);
            split_bf(az, hs.z, ls.z);
            split_bf(aw, hs.w, ls.w);
            *(ushort4*)(ohi + d * 256 + lane * 4) = hs;
            *(ushort4*)(olo + d * 256 + lane * 4) = ls;
        }
    }
}

// ---------------- single cooperative mega-kernel ----------------
__global__ __launch_bounds__(256, 3) void mega(MegaP p)
{
    cg::grid_group grid = cg::this_grid();
    int tid = threadIdx.x;
    int gt = blockIdx.x * 256 + tid;
    const int T = gridDim.x * 256;
    int wave = gt >> 6;
    int lane = tid & 63;
    const int NW = T >> 6;

    // ---- phase A: weights + x split + deg zero ----
    for (int i = gt; i < 131072; i += T) weights_body(i, p);
    for (int i = gt; i < p.N * 64; i += T) {
        float4 v = *(const float4*)(p.x + i * 4);
        ushort4 hs, ls;
        split_bf(v.x, hs.x, ls.x);
        split_bf(v.y, hs.y, ls.y);
        split_bf(v.z, hs.z, ls.z);
        split_bf(v.w, hs.w, ls.w);
        *(ushort4*)(p.xhi + i * 4) = hs;
        *(ushort4*)(p.xlo + i * 4) = ls;
    }
    for (int i = gt; i < p.N; i += T) p.deg[i] = 0;
    __threadfence(); grid.sync();

    // ---- phase B: degree histogram ----
    for (int e = gt; e < p.E_total; e += T) {
        int d = (e < p.E_real) ? p.ei[p.E_real + e] : (e - p.E_real);
        atomicAdd(&p.deg[d], 1);
    }
    __threadfence(); grid.sync();

    // ---- phase C: exclusive scan (block 0) ----
    if (blockIdx.x == 0) {
        __shared__ int sums[256];
        int per = (p.N + 255) / 256;
        int start = tid * per;
        int end = start + per; if (end > p.N) end = p.N; if (start > p.N) start = p.N;
        int s = 0;
        for (int i = start; i < end; i++) s += p.deg[i];
        sums[tid] = s;
        __syncthreads();
        for (int off = 1; off < 256; off <<= 1) {
            int v = (tid >= off) ? sums[tid - off] : 0;
            __syncthreads();
            sums[tid] += v;
            __syncthreads();
        }
        int prefix = (tid == 0) ? 0 : sums[tid - 1];
        for (int i = start; i < end; i++) {
            p.rowptr[i] = prefix;
            p.cursor[i] = prefix;
            prefix += p.deg[i];
        }
        if (tid == 255) p.rowptr[p.N] = sums[255];
    }
    __threadfence(); grid.sync();

    // ---- phase D: CSR fill ----
    for (int e = gt; e < p.E_total; e += T) {
        int s, d;
        if (e < p.E_real) { s = p.ei[e]; d = p.ei[p.E_real + e]; }
        else              { s = d = e - p.E_real; }
        int pos = atomicAdd(&p.cursor[d], 1);
        p.csr_src[pos] = s;
    }
    __threadfence(); grid.sync();

    // ---- layer 0 ----
    gemm_phase(p.xhi, p.xlo, p.whi0, p.wlo0, p.effS0, p.effD0, p.xp, p.ssrc, p.sdst,
               p.N, wave, lane, NW);
    __threadfence(); grid.sync();
    agg_phase(p.rowptr, p.csr_src, p.xp, p.ssrc, p.sdst, nullptr, p.hbhi, p.hblo,
              p.N, 1, wave, lane, NW);
    __threadfence(); grid.sync();

    // ---- layer 1 ----
    gemm_phase(p.hbhi, p.hblo, p.whi1, p.wlo1, p.effS1, p.effD1, p.xp, p.ssrc, p.sdst,
               p.N, wave, lane, NW);
    __threadfence(); grid.sync();
    agg_phase(p.rowptr, p.csr_src, p.xp, p.ssrc, p.sdst, p.out, nullptr, nullptr,
              p.N, 2, wave, lane, NW);
}

// ---------------- fallback kernels (identical to R5 path) ----------------

__global__ void prep_all_fb(MegaP p)
{
    int b = blockIdx.x;
    int t = threadIdx.x;
    if (b < 512) { weights_body(b * 256 + t, p); return; }
    int cb = b - 512;
    int convB = (p.N * 64 + 255) / 256;
    if (cb < convB) {
        int i = cb * 256 + t;
        if (i >= p.N * 64) return;
        float4 v = *(const float4*)(p.x + i * 4);
        ushort4 hs, ls;
        split_bf(v.x, hs.x, ls.x);
        split_bf(v.y, hs.y, ls.y);
        split_bf(v.z, hs.z, ls.z);
        split_bf(v.w, hs.w, ls.w);
        *(ushort4*)(p.xhi + i * 4) = hs;
        *(ushort4*)(p.xlo + i * 4) = ls;
        return;
    }
    int zi = (cb - convB) * 256 + t;
    if (zi < p.N) p.deg[zi] = 0;
}

__global__ void hist_fb(MegaP p)
{
    int e = blockIdx.x * blockDim.x + threadIdx.x;
    if (e >= p.E_total) return;
    int d = (e < p.E_real) ? p.ei[p.E_real + e] : (e - p.E_real);
    atomicAdd(&p.deg[d], 1);
}

__global__ __launch_bounds__(1024) void scan_fb(MegaP p)
{
    __shared__ int sums[1024];
    int t = threadIdx.x;
    int N = p.N;
    int per = (N + 1023) / 1024;
    int start = t * per;
    int end = start + per; if (end > N) end = N; if (start > N) start = N;
    int s = 0;
    for (int i = start; i < end; i++) s += p.deg[i];
    sums[t] = s;
    __syncthreads();
    for (int off = 1; off < 1024; off <<= 1) {
        int v = (t >= off) ? sums[t - off] : 0;
        __syncthreads();
        sums[t] += v;
        __syncthreads();
    }
    int prefix = (t == 0) ? 0 : sums[t - 1];
    for (int i = start; i < end; i++) {
        p.rowptr[i] = prefix;
        p.cursor[i] = prefix;
        prefix += p.deg[i];
    }
    if (t == 1023) p.rowptr[N] = sums[1023];
}

__global__ void fill_fb(MegaP p)
{
    int e = blockIdx.x * blockDim.x + threadIdx.x;
    if (e >= p.E_total) return;
    int s, d;
    if (e < p.E_real) { s = p.ei[e]; d = p.ei[p.E_real + e]; }
    else              { s = d = e - p.E_real; }
    int pos = atomicAdd(&p.cursor[d], 1);
    p.csr_src[pos] = s;
}

__global__ __launch_bounds__(64) void gemm_fb(MegaP p, int layer)
{
    int wave = blockIdx.y * 4 + blockIdx.x;     // one wave per block; tile id
    int lane = threadIdx.x;
    int tiles = 4 * ((p.N + 15) / 16);
    if (wave >= tiles) return;
    if (layer)
        gemm_phase(p.hbhi, p.hblo, p.whi1, p.wlo1, p.effS1, p.effD1, p.xp, p.ssrc, p.sdst,
                   p.N, wave, lane, tiles);
    else
        gemm_phase(p.xhi, p.xlo, p.whi0, p.wlo0, p.effS0, p.effD0, p.xp, p.ssrc, p.sdst,
                   p.N, wave, lane, tiles);
}

__global__ __launch_bounds__(256) void agg_fb(MegaP p, int mode)
{
    int gid = blockIdx.x * blockDim.x + threadIdx.x;
    int d = gid >> 6;
    if (d >= p.N) return;
    int lane = threadIdx.x & 63;
    if (mode == 2)
        agg_phase(p.rowptr, p.csr_src, p.xp, p.ssrc, p.sdst, p.out, nullptr, nullptr,
                  p.N, 2, d, lane, p.N);
    else
        agg_phase(p.rowptr, p.csr_src, p.xp, p.ssrc, p.sdst, nullptr, p.hbhi, p.hblo,
                  p.N, 1, d, lane, p.N);
}

extern "C" void kernel_launch(void* const* d_in, const int* in_sizes, int n_in,
                              void* d_out, int out_size, void* d_ws, size_t ws_size,
                              hipStream_t stream)
{
    MegaP p;
    p.x  = (const float*)d_in[0];
    p.ei = (const int*)d_in[1];
    p.W0 = (const float*)d_in[2];  p.A0 = (const float*)d_in[3];  p.B0 = (const float*)d_in[4];
    p.as0 = (const float*)d_in[5]; p.ad0 = (const float*)d_in[6];
    p.As0 = (const float*)d_in[7]; p.Bs0 = (const float*)d_in[8];
    p.Ad0 = (const float*)d_in[9]; p.Bd0 = (const float*)d_in[10];
    p.W1 = (const float*)d_in[11]; p.A1 = (const float*)d_in[12]; p.B1 = (const float*)d_in[13];
    p.as1 = (const float*)d_in[14]; p.ad1 = (const float*)d_in[15];
    p.As1 = (const float*)d_in[16]; p.Bs1 = (const float*)d_in[17];
    p.Ad1 = (const float*)d_in[18]; p.Bd1 = (const float*)d_in[19];

    p.N = in_sizes[0] / 256;          // 10000
    p.E_real = in_sizes[1] / 2;       // 160000
    p.E_total = p.E_real + p.N;       // 170000

    ushort_t* ws16 = (ushort_t*)d_ws;
    p.whi0 = ws16;                 p.wlo0 = p.whi0 + 65536;
    p.whi1 = p.wlo0 + 65536;       p.wlo1 = p.whi1 + 65536;
    p.xhi  = p.wlo1 + 65536;       p.xlo  = p.xhi + 2560000;
    p.hbhi = p.xlo + 2560000;      p.hblo = p.hbhi + 2560000;
    float* f = (float*)(p.hblo + 2560000);
    p.effS0 = f;        p.effD0 = f + 256;
    p.effS1 = f + 512;  p.effD1 = f + 768;
    p.xp   = f + 1024;              // N*256
    p.ssrc = p.xp + 2560000;        // N*8
    p.sdst = p.ssrc + 80000;
    p.deg     = (int*)(p.sdst + 80000);
    p.rowptr  = p.deg + 10016;
    p.cursor  = p.rowptr + 10016;
    p.csr_src = p.cursor + 10016;
    p.out = (float*)d_out;

    void* args[] = { &p };
    hipError_t err = hipLaunchCooperativeKernel((void*)mega, dim3(768), dim3(256),
                                                args, 0, stream);
    if (err != hipSuccess) {
        // fallback: identical 8-kernel path
        int convB = (p.N * 64 + 255) / 256;
        int zeroB = (p.N + 255) / 256;
        prep_all_fb<<<512 + convB + zeroB, 256, 0, stream>>>(p);
        hist_fb<<<(p.E_total + 255) / 256, 256, 0, stream>>>(p);
        scan_fb<<<1, 1024, 0, stream>>>(p);
        fill_fb<<<(p.E_total + 255) / 256, 256, 0, stream>>>(p);
        dim3 gg(4, (p.N + 15) / 16);
        int aggBlocks = (p.N * 64 + 255) / 256;
        gemm_fb<<<gg, 64, 0, stream>>>(p, 0);
        agg_fb<<<aggBlocks, 256, 0, stream>>>(p, 1);
        gemm_fb<<<gg, 64, 0, stream>>>(p, 1);
        agg_fb<<<aggBlocks, 256, 0, stream>>>(p, 2);
    }
}

// Round 7
// 196.109 us; speedup vs baseline: 6.9546x; 6.9546x over previous
//
#include <hip/hip_runtime.h>

#define LORA_SCALE 4.0f
#define ATT_SCALE 8.0f
#define NEG_SLOPE 0.2f
#define ELLW 128

typedef __attribute__((ext_vector_type(8))) short bf16x8;
typedef __attribute__((ext_vector_type(4))) float f32x4;
typedef unsigned short ushort_t;
typedef unsigned int uint_t;

__device__ inline ushort_t f2bf(float f) {
    uint_t u = __float_as_uint(f);
    u += 0x7fff + ((u >> 16) & 1);     // RNE
    return (ushort_t)(u >> 16);
}
__device__ inline float bf2f(ushort_t h) {
    return __uint_as_float(((uint_t)h) << 16);
}
__device__ inline void split_bf(float f, ushort_t& h, ushort_t& l) {
    h = f2bf(f);
    l = f2bf(f - bf2f(h));
}

// ---------- fused prep: weights(2 layers) + x->bf16 split + cnt zero ----------
__global__ void prep_all(const float* __restrict__ W0, const float* __restrict__ A0,
                         const float* __restrict__ B0,
                         const float* __restrict__ att_s0, const float* __restrict__ att_d0,
                         const float* __restrict__ As0, const float* __restrict__ Bs0,
                         const float* __restrict__ Ad0, const float* __restrict__ Bd0,
                         const float* __restrict__ W1, const float* __restrict__ A1,
                         const float* __restrict__ B1,
                         const float* __restrict__ att_s1, const float* __restrict__ att_d1,
                         const float* __restrict__ As1, const float* __restrict__ Bs1,
                         const float* __restrict__ Ad1, const float* __restrict__ Bd1,
                         ushort_t* __restrict__ whi0, ushort_t* __restrict__ wlo0,
                         ushort_t* __restrict__ whi1, ushort_t* __restrict__ wlo1,
                         float* __restrict__ effS0, float* __restrict__ effD0,
                         float* __restrict__ effS1, float* __restrict__ effD1,
                         const float* __restrict__ x, ushort_t* __restrict__ xhi,
                         ushort_t* __restrict__ xlo, int* __restrict__ cnt, int N)
{
    int b = blockIdx.x;
    int t = threadIdx.x;
    if (b < 512) {
        int layer = b >> 8;
        int i = (b & 255) * 256 + t;
        const float* W = layer ? W1 : W0;
        const float* A = layer ? A1 : A0;
        const float* B = layer ? B1 : B0;
        int r = i >> 8, c = i & 255;
        float acc = W[i];
        #pragma unroll
        for (int k = 0; k < 8; k++) acc += LORA_SCALE * B[r * 8 + k] * A[k * 256 + c];
        ushort_t h, l;
        split_bf(acc, h, l);
        if (layer) { whi1[i] = h; wlo1[i] = l; }
        else       { whi0[i] = h; wlo0[i] = l; }
        if (i < 256) {
            int c2 = i & 31;
            const float* as_ = layer ? att_s1 : att_s0;
            const float* ad_ = layer ? att_d1 : att_d0;
            const float* As = layer ? As1 : As0;
            const float* Bs = layer ? Bs1 : Bs0;
            const float* Ad = layer ? Ad1 : Ad0;
            const float* Bd = layer ? Bd1 : Bd0;
            float es = as_[i], ed = ad_[i];
            #pragma unroll
            for (int k = 0; k < 4; k++) {
                es += ATT_SCALE * Bs[k] * As[k * 32 + c2];
                ed += ATT_SCALE * Bd[k] * Ad[k * 32 + c2];
            }
            if (layer) { effS1[i] = es; effD1[i] = ed; }
            else       { effS0[i] = es; effD0[i] = ed; }
        }
        return;
    }
    int cb = b - 512;
    int convB = (N * 64 + 255) / 256;
    if (cb < convB) {
        int i = cb * 256 + t;
        if (i >= N * 64) return;
        float4 v = *(const float4*)(x + i * 4);
        ushort4 hs, ls;
        split_bf(v.x, hs.x, ls.x);
        split_bf(v.y, hs.y, ls.y);
        split_bf(v.z, hs.z, ls.z);
        split_bf(v.w, hs.w, ls.w);
        *(ushort4*)(xhi + i * 4) = hs;
        *(ushort4*)(xlo + i * 4) = ls;
        return;
    }
    int zi = (cb - convB) * 256 + t;
    if (zi < N) cnt[zi] = 0;
}

// ---------- ELL build: single atomic-append pass ----------
__global__ void fill_ell(const int* __restrict__ ei, int E_real, int E_total,
                         int* __restrict__ cnt, int* __restrict__ ell)
{
    int e = blockIdx.x * blockDim.x + threadIdx.x;
    if (e >= E_total) return;
    int s, d;
    if (e < E_real) { s = ei[e]; d = ei[E_real + e]; }
    else            { s = d = e - E_real; }
    int pos = atomicAdd(&cnt[d], 1);
    if (pos < ELLW) ell[d * ELLW + pos] = s;
}

// ---------- MFMA GEMM + fused attention scores; C stored as bf16 ----------
// one wave per block: 16 rows x 64 cols (= 2 complete heads). grid = (4, M/16)
__global__ __launch_bounds__(64) void gemm_fused(
    const ushort_t* __restrict__ Ahi, const ushort_t* __restrict__ Alo,
    const ushort_t* __restrict__ Bhi, const ushort_t* __restrict__ Blo,
    const float* __restrict__ effS, const float* __restrict__ effD,
    ushort_t* __restrict__ Cb, float* __restrict__ ssrc, float* __restrict__ sdst, int M)
{
    const int K = 256;
    int lane = threadIdx.x;
    int quad = lane >> 4;
    int l16 = lane & 15;
    int m0 = blockIdx.y * 16;
    int n0 = blockIdx.x * 64;
    int mr = m0 + l16; if (mr >= M) mr = M - 1;

    const ushort_t* ah = Ahi + mr * K + quad * 8;
    const ushort_t* al = Alo + mr * K + quad * 8;
    const ushort_t* bh = Bhi + (n0 + l16) * K + quad * 8;
    const ushort_t* bl = Blo + (n0 + l16) * K + quad * 8;

    f32x4 acc[4] = {};
    #pragma unroll
    for (int k0 = 0; k0 < K; k0 += 32) {
        bf16x8 a_hi = *(const bf16x8*)(ah + k0);
        bf16x8 a_lo = *(const bf16x8*)(al + k0);
        #pragma unroll
        for (int t = 0; t < 4; t++) {
            bf16x8 b_hi = *(const bf16x8*)(bh + t * 16 * K + k0);
            bf16x8 b_lo = *(const bf16x8*)(bl + t * 16 * K + k0);
            acc[t] = __builtin_amdgcn_mfma_f32_16x16x32_bf16(a_hi, b_hi, acc[t], 0, 0, 0);
            acc[t] = __builtin_amdgcn_mfma_f32_16x16x32_bf16(a_hi, b_lo, acc[t], 0, 0, 0);
            acc[t] = __builtin_amdgcn_mfma_f32_16x16x32_bf16(a_lo, b_hi, acc[t], 0, 0, 0);
        }
    }

    // ---- store C as bf16: C/D layout col = l16, row = quad*4 + reg ----
    #pragma unroll
    for (int t = 0; t < 4; t++) {
        #pragma unroll
        for (int r = 0; r < 4; r++) {
            int m = m0 + quad * 4 + r;
            if (m < M) Cb[m * 256 + n0 + t * 16 + l16] = f2bf(acc[t][r]);
        }
    }

    // ---- fused scores (fp32, from accumulators) ----
    int h0 = n0 >> 5;
    float vs[2][4], vd[2][4];
    #pragma unroll
    for (int g = 0; g < 2; g++) {
        float e0s = effS[n0 + 32 * g + l16];
        float e1s = effS[n0 + 32 * g + 16 + l16];
        float e0d = effD[n0 + 32 * g + l16];
        float e1d = effD[n0 + 32 * g + 16 + l16];
        #pragma unroll
        for (int r = 0; r < 4; r++) {
            vs[g][r] = acc[2 * g][r] * e0s + acc[2 * g + 1][r] * e1s;
            vd[g][r] = acc[2 * g][r] * e0d + acc[2 * g + 1][r] * e1d;
        }
    }
    #pragma unroll
    for (int m = 1; m <= 8; m <<= 1) {
        #pragma unroll
        for (int g = 0; g < 2; g++)
            #pragma unroll
            for (int r = 0; r < 4; r++) {
                vs[g][r] += __shfl_xor(vs[g][r], m);
                vd[g][r] += __shfl_xor(vd[g][r], m);
            }
    }
    if (l16 == 0) {
        #pragma unroll
        for (int g = 0; g < 2; g++)
            #pragma unroll
            for (int r = 0; r < 4; r++) {
                int m = m0 + quad * 4 + r;
                if (m < M) {
                    ssrc[m * 8 + h0 + g] = vs[g][r];
                    sdst[m * 8 + h0 + g] = vd[g][r];
                }
            }
    }
}

// ---------- gather-aggregate over ELL, bf16 gathers, predicated unroll-8 ----------
// one wave per node. mode 1: ELU -> bf16 hi/lo 256ch; mode 2: head-mean -> 32ch fp32
__global__ __launch_bounds__(256) void ell_agg(const int* __restrict__ cnt,
                                               const int* __restrict__ ell,
                                               const ushort_t* __restrict__ xpb,
                                               const float* __restrict__ ssrc,
                                               const float* __restrict__ sdst,
                                               float* __restrict__ out,
                                               ushort_t* __restrict__ ohi,
                                               ushort_t* __restrict__ olo,
                                               int N, int mode)
{
    int gid = blockIdx.x * blockDim.x + threadIdx.x;
    int d = gid >> 6;
    if (d >= N) return;
    int lane = threadIdx.x & 63;
    int h = lane >> 3;
    float ssrc_h = ssrc[d * 8 + h];
    const int* row = ell + d * ELLW;
    int end = cnt[d];
    int lim = end - 1;                 // deg >= 1 (self-loop)

    float den = 0.f, ax = 0.f, ay = 0.f, az = 0.f, aw = 0.f;
    for (int i = 0; i < end; i += 8) {
        int idx[8];
        #pragma unroll
        for (int j = 0; j < 8; j++) {
            int ii = i + j;
            idx[j] = row[ii < end ? ii : lim];
        }
        float t[8];
        #pragma unroll
        for (int j = 0; j < 8; j++) t[j] = sdst[idx[j] * 8 + h];
        ushort4 v[8];
        #pragma unroll
        for (int j = 0; j < 8; j++) v[j] = *(const ushort4*)(xpb + idx[j] * 256 + lane * 4);
        float w[8];
        #pragma unroll
        for (int j = 0; j < 8; j++) {
            float al = ssrc_h + t[j];
            al = al > 0.f ? al : NEG_SLOPE * al;
            w[j] = (i + j < end) ? __expf(al) : 0.f;
        }
        #pragma unroll
        for (int j = 0; j < 8; j++) {
            den += w[j];
            ax += bf2f(v[j].x) * w[j];
            ay += bf2f(v[j].y) * w[j];
            az += bf2f(v[j].z) * w[j];
            aw += bf2f(v[j].w) * w[j];
        }
    }
    float inv = 1.f / den;
    ax *= inv; ay *= inv; az *= inv; aw *= inv;

    if (mode == 2) {
        #pragma unroll
        for (int m = 8; m <= 32; m <<= 1) {
            ax += __shfl_xor(ax, m);
            ay += __shfl_xor(ay, m);
            az += __shfl_xor(az, m);
            aw += __shfl_xor(aw, m);
        }
        if (lane < 8) {
            float4 r = { ax * 0.125f, ay * 0.125f, az * 0.125f, aw * 0.125f };
            *(float4*)(out + d * 32 + lane * 4) = r;
        }
        return;
    }
    ax = ax > 0.f ? ax : (__expf(ax) - 1.f);
    ay = ay > 0.f ? ay : (__expf(ay) - 1.f);
    az = az > 0.f ? az : (__expf(az) - 1.f);
    aw = aw > 0.f ? aw : (__expf(aw) - 1.f);
    ushort4 hs, ls;
    split_bf(ax, hs.x, ls.x);
    split_bf(ay, hs.y, ls.y);
    split_bf(az, hs.z, ls.z);
    split_bf(aw, hs.w, ls.w);
    *(ushort4*)(ohi + d * 256 + lane * 4) = hs;
    *(ushort4*)(olo + d * 256 + lane * 4) = ls;
}

extern "C" void kernel_launch(void* const* d_in, const int* in_sizes, int n_in,
                              void* d_out, int out_size, void* d_ws, size_t ws_size,
                              hipStream_t stream)
{
    const float* x  = (const float*)d_in[0];
    const int*   ei = (const int*)d_in[1];
    const float* W0 = (const float*)d_in[2];
    const float* A0 = (const float*)d_in[3];
    const float* B0 = (const float*)d_in[4];
    const float* att_s0 = (const float*)d_in[5];
    const float* att_d0 = (const float*)d_in[6];
    const float* As0 = (const float*)d_in[7];
    const float* Bs0 = (const float*)d_in[8];
    const float* Ad0 = (const float*)d_in[9];
    const float* Bd0 = (const float*)d_in[10];
    const float* W1 = (const float*)d_in[11];
    const float* A1 = (const float*)d_in[12];
    const float* B1 = (const float*)d_in[13];
    const float* att_s1 = (const float*)d_in[14];
    const float* att_d1 = (const float*)d_in[15];
    const float* As1 = (const float*)d_in[16];
    const float* Bs1 = (const float*)d_in[17];
    const float* Ad1 = (const float*)d_in[18];
    const float* Bd1 = (const float*)d_in[19];

    const int N = in_sizes[0] / 256;      // 10000
    const int E_real = in_sizes[1] / 2;   // 160000
    const int E_total = E_real + N;       // 170000

    // ---- workspace layout ----
    ushort_t* whi0 = (ushort_t*)d_ws;        // 65536 each
    ushort_t* wlo0 = whi0 + 65536;
    ushort_t* whi1 = wlo0 + 65536;
    ushort_t* wlo1 = whi1 + 65536;
    ushort_t* xhi  = wlo1 + 65536;           // N*256
    ushort_t* xlo  = xhi + 2560000;
    ushort_t* hbhi = xlo + 2560000;
    ushort_t* hblo = hbhi + 2560000;
    ushort_t* xpb  = hblo + 2560000;         // N*256 bf16 projected features
    float* effS0 = (float*)(xpb + 2560000);
    float* effD0 = effS0 + 256;
    float* effS1 = effD0 + 256;
    float* effD1 = effS1 + 256;
    float* ssrc  = effD1 + 256;              // N*8
    float* sdst  = ssrc + 80000;
    int* cnt = (int*)(sdst + 80000);         // N
    int* ell = cnt + 10016;                  // N*ELLW

    // ---- prep (weights, x split, cnt zero) + ELL build ----
    int convB = (N * 64 + 255) / 256;
    int zeroB = (N + 255) / 256;
    prep_all<<<512 + convB + zeroB, 256, 0, stream>>>(
        W0, A0, B0, att_s0, att_d0, As0, Bs0, Ad0, Bd0,
        W1, A1, B1, att_s1, att_d1, As1, Bs1, Ad1, Bd1,
        whi0, wlo0, whi1, wlo1, effS0, effD0, effS1, effD1,
        x, xhi, xlo, cnt, N);
    fill_ell<<<(E_total + 255) / 256, 256, 0, stream>>>(ei, E_real, E_total, cnt, ell);

    dim3 gg(4, (N + 15) / 16);
    int aggBlocks = (N * 64 + 255) / 256;

    // ---------------- layer 0 ----------------
    gemm_fused<<<gg, 64, 0, stream>>>(xhi, xlo, whi0, wlo0, effS0, effD0, xpb, ssrc, sdst, N);
    ell_agg<<<aggBlocks, 256, 0, stream>>>(cnt, ell, xpb, ssrc, sdst,
                                           nullptr, hbhi, hblo, N, 1);

    // ---------------- layer 1 ----------------
    gemm_fused<<<gg, 64, 0, stream>>>(hbhi, hblo, whi1, wlo1, effS1, effD1, xpb, ssrc, sdst, N);
    ell_agg<<<aggBlocks, 256, 0, stream>>>(cnt, ell, xpb, ssrc, sdst,
                                           (float*)d_out, nullptr, nullptr, N, 2);
}

// Round 8
// 193.093 us; speedup vs baseline: 7.0632x; 1.0156x over previous
//
#include <hip/hip_runtime.h>

#define LORA_SCALE 4.0f
#define ATT_SCALE 8.0f
#define NEG_SLOPE 0.2f
#define ELLW 64

typedef __attribute__((ext_vector_type(8))) short bf16x8;
typedef __attribute__((ext_vector_type(4))) float f32x4;
typedef unsigned short ushort_t;
typedef unsigned int uint_t;

__device__ inline ushort_t f2bf(float f) {
    uint_t u = __float_as_uint(f);
    u += 0x7fff + ((u >> 16) & 1);     // RNE
    return (ushort_t)(u >> 16);
}
__device__ inline float bf2f(ushort_t h) {
    return __uint_as_float(((uint_t)h) << 16);
}
__device__ inline void split_bf(float f, ushort_t& h, ushort_t& l) {
    h = f2bf(f);
    l = f2bf(f - bf2f(h));
}

// ---------- fused prep: weights(2 layers) + x->bf16 split + ELL fill ----------
// requires cnt[] zeroed beforehand (hipMemsetAsync)
__global__ void prep_all(const float* __restrict__ W0, const float* __restrict__ A0,
                         const float* __restrict__ B0,
                         const float* __restrict__ att_s0, const float* __restrict__ att_d0,
                         const float* __restrict__ As0, const float* __restrict__ Bs0,
                         const float* __restrict__ Ad0, const float* __restrict__ Bd0,
                         const float* __restrict__ W1, const float* __restrict__ A1,
                         const float* __restrict__ B1,
                         const float* __restrict__ att_s1, const float* __restrict__ att_d1,
                         const float* __restrict__ As1, const float* __restrict__ Bs1,
                         const float* __restrict__ Ad1, const float* __restrict__ Bd1,
                         ushort_t* __restrict__ whi0, ushort_t* __restrict__ wlo0,
                         ushort_t* __restrict__ whi1, ushort_t* __restrict__ wlo1,
                         float* __restrict__ effS0, float* __restrict__ effD0,
                         float* __restrict__ effS1, float* __restrict__ effD1,
                         const float* __restrict__ x, ushort_t* __restrict__ xhi,
                         ushort_t* __restrict__ xlo,
                         const int* __restrict__ ei, int E_real, int E_total,
                         int* __restrict__ cnt, int* __restrict__ ell, int N)
{
    int b = blockIdx.x;
    int t = threadIdx.x;
    if (b < 512) {
        int layer = b >> 8;
        int i = (b & 255) * 256 + t;
        const float* W = layer ? W1 : W0;
        const float* A = layer ? A1 : A0;
        const float* B = layer ? B1 : B0;
        int r = i >> 8, c = i & 255;
        float acc = W[i];
        #pragma unroll
        for (int k = 0; k < 8; k++) acc += LORA_SCALE * B[r * 8 + k] * A[k * 256 + c];
        ushort_t h, l;
        split_bf(acc, h, l);
        if (layer) { whi1[i] = h; wlo1[i] = l; }
        else       { whi0[i] = h; wlo0[i] = l; }
        if (i < 256) {
            int c2 = i & 31;
            const float* as_ = layer ? att_s1 : att_s0;
            const float* ad_ = layer ? att_d1 : att_d0;
            const float* As = layer ? As1 : As0;
            const float* Bs = layer ? Bs1 : Bs0;
            const float* Ad = layer ? Ad1 : Ad0;
            const float* Bd = layer ? Bd1 : Bd0;
            float es = as_[i], ed = ad_[i];
            #pragma unroll
            for (int k = 0; k < 4; k++) {
                es += ATT_SCALE * Bs[k] * As[k * 32 + c2];
                ed += ATT_SCALE * Bd[k] * Ad[k * 32 + c2];
            }
            if (layer) { effS1[i] = es; effD1[i] = ed; }
            else       { effS0[i] = es; effD0[i] = ed; }
        }
        return;
    }
    int cb = b - 512;
    int convB = (N * 64 + 255) / 256;
    if (cb < convB) {
        int i = cb * 256 + t;
        if (i >= N * 64) return;
        float4 v = *(const float4*)(x + i * 4);
        ushort4 hs, ls;
        split_bf(v.x, hs.x, ls.x);
        split_bf(v.y, hs.y, ls.y);
        split_bf(v.z, hs.z, ls.z);
        split_bf(v.w, hs.w, ls.w);
        *(ushort4*)(xhi + i * 4) = hs;
        *(ushort4*)(xlo + i * 4) = ls;
        return;
    }
    // ---- ELL fill ----
    int e = (cb - convB) * 256 + t;
    if (e >= E_total) return;
    int s, d;
    if (e < E_real) { s = ei[e]; d = ei[E_real + e]; }
    else            { s = d = e - E_real; }
    int pos = atomicAdd(&cnt[d], 1);
    if (pos < ELLW) ell[d * ELLW + pos] = s;
}

// ---------- MFMA GEMM + fused attention scores; C stored as bf16 ----------
// one wave per block: 16 rows x 64 cols (= 2 complete heads). grid = (4, M/16)
__global__ __launch_bounds__(64) void gemm_fused(
    const ushort_t* __restrict__ Ahi, const ushort_t* __restrict__ Alo,
    const ushort_t* __restrict__ Bhi, const ushort_t* __restrict__ Blo,
    const float* __restrict__ effS, const float* __restrict__ effD,
    ushort_t* __restrict__ Cb, float* __restrict__ ssrc, float* __restrict__ sdst, int M)
{
    const int K = 256;
    int lane = threadIdx.x;
    int quad = lane >> 4;
    int l16 = lane & 15;
    int m0 = blockIdx.y * 16;
    int n0 = blockIdx.x * 64;
    int mr = m0 + l16; if (mr >= M) mr = M - 1;

    const ushort_t* ah = Ahi + mr * K + quad * 8;
    const ushort_t* al = Alo + mr * K + quad * 8;
    const ushort_t* bh = Bhi + (n0 + l16) * K + quad * 8;
    const ushort_t* bl = Blo + (n0 + l16) * K + quad * 8;

    f32x4 acc[4] = {};
    #pragma unroll
    for (int k0 = 0; k0 < K; k0 += 32) {
        bf16x8 a_hi = *(const bf16x8*)(ah + k0);
        bf16x8 a_lo = *(const bf16x8*)(al + k0);
        #pragma unroll
        for (int t = 0; t < 4; t++) {
            bf16x8 b_hi = *(const bf16x8*)(bh + t * 16 * K + k0);
            bf16x8 b_lo = *(const bf16x8*)(bl + t * 16 * K + k0);
            acc[t] = __builtin_amdgcn_mfma_f32_16x16x32_bf16(a_hi, b_hi, acc[t], 0, 0, 0);
            acc[t] = __builtin_amdgcn_mfma_f32_16x16x32_bf16(a_hi, b_lo, acc[t], 0, 0, 0);
            acc[t] = __builtin_amdgcn_mfma_f32_16x16x32_bf16(a_lo, b_hi, acc[t], 0, 0, 0);
        }
    }

    // ---- store C as bf16: C/D layout col = l16, row = quad*4 + reg ----
    #pragma unroll
    for (int t = 0; t < 4; t++) {
        #pragma unroll
        for (int r = 0; r < 4; r++) {
            int m = m0 + quad * 4 + r;
            if (m < M) Cb[m * 256 + n0 + t * 16 + l16] = f2bf(acc[t][r]);
        }
    }

    // ---- fused scores (fp32, from accumulators) ----
    int h0 = n0 >> 5;
    float vs[2][4], vd[2][4];
    #pragma unroll
    for (int g = 0; g < 2; g++) {
        float e0s = effS[n0 + 32 * g + l16];
        float e1s = effS[n0 + 32 * g + 16 + l16];
        float e0d = effD[n0 + 32 * g + l16];
        float e1d = effD[n0 + 32 * g + 16 + l16];
        #pragma unroll
        for (int r = 0; r < 4; r++) {
            vs[g][r] = acc[2 * g][r] * e0s + acc[2 * g + 1][r] * e1s;
            vd[g][r] = acc[2 * g][r] * e0d + acc[2 * g + 1][r] * e1d;
        }
    }
    #pragma unroll
    for (int m = 1; m <= 8; m <<= 1) {
        #pragma unroll
        for (int g = 0; g < 2; g++)
            #pragma unroll
            for (int r = 0; r < 4; r++) {
                vs[g][r] += __shfl_xor(vs[g][r], m);
                vd[g][r] += __shfl_xor(vd[g][r], m);
            }
    }
    if (l16 == 0) {
        #pragma unroll
        for (int g = 0; g < 2; g++)
            #pragma unroll
            for (int r = 0; r < 4; r++) {
                int m = m0 + quad * 4 + r;
                if (m < M) {
                    ssrc[m * 8 + h0 + g] = vs[g][r];
                    sdst[m * 8 + h0 + g] = vd[g][r];
                }
            }
    }
}

// ---------- gather-aggregate over ELL: LDS-staged indices, unroll-8 ----------
// one wave per node. mode 1: ELU -> bf16 hi/lo 256ch; mode 2: head-mean -> 32ch fp32
__global__ __launch_bounds__(256) void ell_agg(const int* __restrict__ cnt,
                                               const int* __restrict__ ell,
                                               const ushort_t* __restrict__ xpb,
                                               const float* __restrict__ ssrc,
                                               const float* __restrict__ sdst,
                                               float* __restrict__ out,
                                               ushort_t* __restrict__ ohi,
                                               ushort_t* __restrict__ olo,
                                               int N, int mode)
{
    __shared__ int sidx[4][ELLW];
    int gid = blockIdx.x * blockDim.x + threadIdx.x;
    int d = gid >> 6;
    if (d >= N) return;
    int w = threadIdx.x >> 6;
    int lane = threadIdx.x & 63;
    int h = lane >> 3;
    float ssrc_h = ssrc[d * 8 + h];
    int end = cnt[d]; if (end > ELLW) end = ELLW;
    const int* row = ell + d * ELLW;
    // stage whole index row in LDS (one coalesced 256B load; clamp OOB slots)
    sidx[w][lane] = row[lane < end ? lane : 0];
    // single-wave write->read: in-order within wave, compiler inserts lgkmcnt wait

    float den = 0.f, ax = 0.f, ay = 0.f, az = 0.f, aw = 0.f;
    for (int i = 0; i < end; i += 8) {
        int idx[8];
        #pragma unroll
        for (int j = 0; j < 8; j++) {
            int ii = i + j;
            idx[j] = sidx[w][ii < end ? ii : 0];
        }
        float t[8];
        #pragma unroll
        for (int j = 0; j < 8; j++) t[j] = sdst[idx[j] * 8 + h];
        ushort4 v[8];
        #pragma unroll
        for (int j = 0; j < 8; j++) v[j] = *(const ushort4*)(xpb + idx[j] * 256 + lane * 4);
        float w8[8];
        #pragma unroll
        for (int j = 0; j < 8; j++) {
            float al = ssrc_h + t[j];
            al = al > 0.f ? al : NEG_SLOPE * al;
            w8[j] = (i + j < end) ? __expf(al) : 0.f;
        }
        #pragma unroll
        for (int j = 0; j < 8; j++) {
            den += w8[j];
            ax += bf2f(v[j].x) * w8[j];
            ay += bf2f(v[j].y) * w8[j];
            az += bf2f(v[j].z) * w8[j];
            aw += bf2f(v[j].w) * w8[j];
        }
    }
    float inv = 1.f / den;
    ax *= inv; ay *= inv; az *= inv; aw *= inv;

    if (mode == 2) {
        #pragma unroll
        for (int m = 8; m <= 32; m <<= 1) {
            ax += __shfl_xor(ax, m);
            ay += __shfl_xor(ay, m);
            az += __shfl_xor(az, m);
            aw += __shfl_xor(aw, m);
        }
        if (lane < 8) {
            float4 r = { ax * 0.125f, ay * 0.125f, az * 0.125f, aw * 0.125f };
            *(float4*)(out + d * 32 + lane * 4) = r;
        }
        return;
    }
    ax = ax > 0.f ? ax : (__expf(ax) - 1.f);
    ay = ay > 0.f ? ay : (__expf(ay) - 1.f);
    az = az > 0.f ? az : (__expf(az) - 1.f);
    aw = aw > 0.f ? aw : (__expf(aw) - 1.f);
    ushort4 hs, ls;
    split_bf(ax, hs.x, ls.x);
    split_bf(ay, hs.y, ls.y);
    split_bf(az, hs.z, ls.z);
    split_bf(aw, hs.w, ls.w);
    *(ushort4*)(ohi + d * 256 + lane * 4) = hs;
    *(ushort4*)(olo + d * 256 + lane * 4) = ls;
}

extern "C" void kernel_launch(void* const* d_in, const int* in_sizes, int n_in,
                              void* d_out, int out_size, void* d_ws, size_t ws_size,
                              hipStream_t stream)
{
    const float* x  = (const float*)d_in[0];
    const int*   ei = (const int*)d_in[1];
    const float* W0 = (const float*)d_in[2];
    const float* A0 = (const float*)d_in[3];
    const float* B0 = (const float*)d_in[4];
    const float* att_s0 = (const float*)d_in[5];
    const float* att_d0 = (const float*)d_in[6];
    const float* As0 = (const float*)d_in[7];
    const float* Bs0 = (const float*)d_in[8];
    const float* Ad0 = (const float*)d_in[9];
    const float* Bd0 = (const float*)d_in[10];
    const float* W1 = (const float*)d_in[11];
    const float* A1 = (const float*)d_in[12];
    const float* B1 = (const float*)d_in[13];
    const float* att_s1 = (const float*)d_in[14];
    const float* att_d1 = (const float*)d_in[15];
    const float* As1 = (const float*)d_in[16];
    const float* Bs1 = (const float*)d_in[17];
    const float* Ad1 = (const float*)d_in[18];
    const float* Bd1 = (const float*)d_in[19];

    const int N = in_sizes[0] / 256;      // 10000
    const int E_real = in_sizes[1] / 2;   // 160000
    const int E_total = E_real + N;       // 170000

    // ---- workspace layout ----
    ushort_t* whi0 = (ushort_t*)d_ws;        // 65536 each
    ushort_t* wlo0 = whi0 + 65536;
    ushort_t* whi1 = wlo0 + 65536;
    ushort_t* wlo1 = whi1 + 65536;
    ushort_t* xhi  = wlo1 + 65536;           // N*256
    ushort_t* xlo  = xhi + 2560000;
    ushort_t* hbhi = xlo + 2560000;
    ushort_t* hblo = hbhi + 2560000;
    ushort_t* xpb  = hblo + 2560000;         // N*256 bf16 projected features
    float* effS0 = (float*)(xpb + 2560000);
    float* effD0 = effS0 + 256;
    float* effS1 = effD0 + 256;
    float* effD1 = effS1 + 256;
    float* ssrc  = effD1 + 256;              // N*8
    float* sdst  = ssrc + 80000;
    int* cnt = (int*)(sdst + 80000);         // N
    int* ell = cnt + 10016;                  // N*ELLW

    // ---- zero cnt, then fused prep (weights + x split + ELL fill) ----
    hipMemsetAsync(cnt, 0, (size_t)N * sizeof(int), stream);
    int convB = (N * 64 + 255) / 256;
    int fillB = (E_total + 255) / 256;
    prep_all<<<512 + convB + fillB, 256, 0, stream>>>(
        W0, A0, B0, att_s0, att_d0, As0, Bs0, Ad0, Bd0,
        W1, A1, B1, att_s1, att_d1, As1, Bs1, Ad1, Bd1,
        whi0, wlo0, whi1, wlo1, effS0, effD0, effS1, effD1,
        x, xhi, xlo, ei, E_real, E_total, cnt, ell, N);

    dim3 gg(4, (N + 15) / 16);
    int aggBlocks = (N * 64 + 255) / 256;

    // ---------------- layer 0 ----------------
    gemm_fused<<<gg, 64, 0, stream>>>(xhi, xlo, whi0, wlo0, effS0, effD0, xpb, ssrc, sdst, N);
    ell_agg<<<aggBlocks, 256, 0, stream>>>(cnt, ell, xpb, ssrc, sdst,
                                           nullptr, hbhi, hblo, N, 1);

    // ---------------- layer 1 ----------------
    gemm_fused<<<gg, 64, 0, stream>>>(hbhi, hblo, whi1, wlo1, effS1, effD1, xpb, ssrc, sdst, N);
    ell_agg<<<aggBlocks, 256, 0, stream>>>(cnt, ell, xpb, ssrc, sdst,
                                           (float*)d_out, nullptr, nullptr, N, 2);
}

// Round 9
// 178.351 us; speedup vs baseline: 7.6470x; 1.0827x over previous
//
#include <hip/hip_runtime.h>

#define LORA_SCALE 4.0f
#define ATT_SCALE 8.0f
#define NEG_SLOPE 0.2f
#define ELLW 64

typedef __attribute__((ext_vector_type(8))) short bf16x8;
typedef __attribute__((ext_vector_type(4))) float f32x4;
typedef unsigned short ushort_t;
typedef unsigned int uint_t;

__device__ inline ushort_t f2bf(float f) {
    uint_t u = __float_as_uint(f);
    u += 0x7fff + ((u >> 16) & 1);     // RNE
    return (ushort_t)(u >> 16);
}
__device__ inline float bf2f(ushort_t h) {
    return __uint_as_float(((uint_t)h) << 16);
}
__device__ inline void split_bf(float f, ushort_t& h, ushort_t& l) {
    h = f2bf(f);
    l = f2bf(f - bf2f(h));
}

// ---------- fused prep: weights(2 layers) + x->bf16 split + ELL fill ----------
// requires cnt[] zeroed beforehand (hipMemsetAsync)
__global__ void prep_all(const float* __restrict__ W0, const float* __restrict__ A0,
                         const float* __restrict__ B0,
                         const float* __restrict__ att_s0, const float* __restrict__ att_d0,
                         const float* __restrict__ As0, const float* __restrict__ Bs0,
                         const float* __restrict__ Ad0, const float* __restrict__ Bd0,
                         const float* __restrict__ W1, const float* __restrict__ A1,
                         const float* __restrict__ B1,
                         const float* __restrict__ att_s1, const float* __restrict__ att_d1,
                         const float* __restrict__ As1, const float* __restrict__ Bs1,
                         const float* __restrict__ Ad1, const float* __restrict__ Bd1,
                         ushort_t* __restrict__ whi0, ushort_t* __restrict__ wlo0,
                         ushort_t* __restrict__ whi1, ushort_t* __restrict__ wlo1,
                         float* __restrict__ effS0, float* __restrict__ effD0,
                         float* __restrict__ effS1, float* __restrict__ effD1,
                         const float* __restrict__ x, ushort_t* __restrict__ xhi,
                         ushort_t* __restrict__ xlo,
                         const int* __restrict__ ei, int E_real, int E_total,
                         int* __restrict__ cnt, int* __restrict__ ell, int N)
{
    int b = blockIdx.x;
    int t = threadIdx.x;
    if (b < 512) {
        int layer = b >> 8;
        int i = (b & 255) * 256 + t;
        const float* W = layer ? W1 : W0;
        const float* A = layer ? A1 : A0;
        const float* B = layer ? B1 : B0;
        int r = i >> 8, c = i & 255;
        float acc = W[i];
        #pragma unroll
        for (int k = 0; k < 8; k++) acc += LORA_SCALE * B[r * 8 + k] * A[k * 256 + c];
        ushort_t h, l;
        split_bf(acc, h, l);
        if (layer) { whi1[i] = h; wlo1[i] = l; }
        else       { whi0[i] = h; wlo0[i] = l; }
        if (i < 256) {
            int c2 = i & 31;
            const float* as_ = layer ? att_s1 : att_s0;
            const float* ad_ = layer ? att_d1 : att_d0;
            const float* As = layer ? As1 : As0;
            const float* Bs = layer ? Bs1 : Bs0;
            const float* Ad = layer ? Ad1 : Ad0;
            const float* Bd = layer ? Bd1 : Bd0;
            float es = as_[i], ed = ad_[i];
            #pragma unroll
            for (int k = 0; k < 4; k++) {
                es += ATT_SCALE * Bs[k] * As[k * 32 + c2];
                ed += ATT_SCALE * Bd[k] * Ad[k * 32 + c2];
            }
            if (layer) { effS1[i] = es; effD1[i] = ed; }
            else       { effS0[i] = es; effD0[i] = ed; }
        }
        return;
    }
    int cb = b - 512;
    int convB = (N * 64 + 255) / 256;
    if (cb < convB) {
        int i = cb * 256 + t;
        if (i >= N * 64) return;
        float4 v = *(const float4*)(x + i * 4);
        ushort4 hs, ls;
        split_bf(v.x, hs.x, ls.x);
        split_bf(v.y, hs.y, ls.y);
        split_bf(v.z, hs.z, ls.z);
        split_bf(v.w, hs.w, ls.w);
        *(ushort4*)(xhi + i * 4) = hs;
        *(ushort4*)(xlo + i * 4) = ls;
        return;
    }
    // ---- ELL fill ----
    int e = (cb - convB) * 256 + t;
    if (e >= E_total) return;
    int s, d;
    if (e < E_real) { s = ei[e]; d = ei[E_real + e]; }
    else            { s = d = e - E_real; }
    int pos = atomicAdd(&cnt[d], 1);
    if (pos < ELLW) ell[d * ELLW + pos] = s;
}

// ---------- MFMA GEMM + fused attention scores; B-tile staged in LDS ----------
// block = 256 threads = 4 waves sharing one 64-col n-tile; wave w owns rows
// m0 = by*64 + w*16. B staged in MFMA-fragment order -> conflict-free ds_read_b128.
// grid = (4, ceil(M/64))
__global__ __launch_bounds__(256) void gemm_fused(
    const ushort_t* __restrict__ Ahi, const ushort_t* __restrict__ Alo,
    const ushort_t* __restrict__ Bhi, const ushort_t* __restrict__ Blo,
    const float* __restrict__ effS, const float* __restrict__ effD,
    ushort_t* __restrict__ Cb, float* __restrict__ ssrc, float* __restrict__ sdst, int M)
{
    __shared__ ushort_t sBh[16384];   // 32 KB: hi fragments
    __shared__ ushort_t sBl[16384];   // 32 KB: lo fragments
    const int K = 256;
    int tid = threadIdx.x;
    int n0 = blockIdx.x * 64;

    // ---- stage B-tile (64 rows x 256 K, hi+lo) into fragment-ordered LDS ----
    // fragment addr for (row rr, k): t=rr>>4, l16=rr&15, kblk=k>>5, quad=(k>>3)&3
    //   dst = (((t*8 + kblk)*4 + quad)*16 + l16)*8
    const ushort_t* srcH = Bhi + (size_t)n0 * K;
    const ushort_t* srcL = Blo + (size_t)n0 * K;
    #pragma unroll
    for (int c = 0; c < 8; c++) {
        int g  = c * 256 + tid;        // chunk id 0..2047 (8 shorts each)
        int rr = g >> 5;               // row 0..63
        int ch = g & 31;               // 8-short chunk within row
        int kblk = ch >> 2, quad = ch & 3;
        int tt = rr >> 4, l16r = rr & 15;
        int dst = (((tt * 8 + kblk) * 4 + quad) * 16 + l16r) * 8;
        *(bf16x8*)&sBh[dst] = *(const bf16x8*)(srcH + rr * K + ch * 8);
        *(bf16x8*)&sBl[dst] = *(const bf16x8*)(srcL + rr * K + ch * 8);
    }
    __syncthreads();

    int w = tid >> 6;
    int lane = tid & 63;
    int quad = lane >> 4;
    int l16 = lane & 15;
    int m0 = blockIdx.y * 64 + w * 16;
    int mr = m0 + l16; if (mr >= M) mr = M - 1;

    const ushort_t* ah = Ahi + mr * K + quad * 8;
    const ushort_t* al = Alo + mr * K + quad * 8;

    f32x4 acc[4] = {};
    #pragma unroll
    for (int kb = 0; kb < 8; kb++) {
        bf16x8 a_hi = *(const bf16x8*)(ah + kb * 32);
        bf16x8 a_lo = *(const bf16x8*)(al + kb * 32);
        #pragma unroll
        for (int t = 0; t < 4; t++) {
            int off = (((t * 8 + kb) * 4 + quad) * 16 + l16) * 8;
            bf16x8 b_hi = *(const bf16x8*)&sBh[off];
            bf16x8 b_lo = *(const bf16x8*)&sBl[off];
            acc[t] = __builtin_amdgcn_mfma_f32_16x16x32_bf16(a_hi, b_hi, acc[t], 0, 0, 0);
            acc[t] = __builtin_amdgcn_mfma_f32_16x16x32_bf16(a_hi, b_lo, acc[t], 0, 0, 0);
            acc[t] = __builtin_amdgcn_mfma_f32_16x16x32_bf16(a_lo, b_hi, acc[t], 0, 0, 0);
        }
    }

    // ---- store C as bf16: C/D layout col = l16, row = quad*4 + reg ----
    #pragma unroll
    for (int t = 0; t < 4; t++) {
        #pragma unroll
        for (int r = 0; r < 4; r++) {
            int m = m0 + quad * 4 + r;
            if (m < M) Cb[m * 256 + n0 + t * 16 + l16] = f2bf(acc[t][r]);
        }
    }

    // ---- fused scores (fp32, from accumulators) ----
    int h0 = n0 >> 5;
    float vs[2][4], vd[2][4];
    #pragma unroll
    for (int g = 0; g < 2; g++) {
        float e0s = effS[n0 + 32 * g + l16];
        float e1s = effS[n0 + 32 * g + 16 + l16];
        float e0d = effD[n0 + 32 * g + l16];
        float e1d = effD[n0 + 32 * g + 16 + l16];
        #pragma unroll
        for (int r = 0; r < 4; r++) {
            vs[g][r] = acc[2 * g][r] * e0s + acc[2 * g + 1][r] * e1s;
            vd[g][r] = acc[2 * g][r] * e0d + acc[2 * g + 1][r] * e1d;
        }
    }
    #pragma unroll
    for (int m = 1; m <= 8; m <<= 1) {
        #pragma unroll
        for (int g = 0; g < 2; g++)
            #pragma unroll
            for (int r = 0; r < 4; r++) {
                vs[g][r] += __shfl_xor(vs[g][r], m);
                vd[g][r] += __shfl_xor(vd[g][r], m);
            }
    }
    if (l16 == 0) {
        #pragma unroll
        for (int g = 0; g < 2; g++)
            #pragma unroll
            for (int r = 0; r < 4; r++) {
                int m = m0 + quad * 4 + r;
                if (m < M) {
                    ssrc[m * 8 + h0 + g] = vs[g][r];
                    sdst[m * 8 + h0 + g] = vd[g][r];
                }
            }
    }
}

// ---------- gather-aggregate over ELL: LDS-staged indices, unroll-8 ----------
// one wave per node. mode 1: ELU -> bf16 hi/lo 256ch; mode 2: head-mean -> 32ch fp32
__global__ __launch_bounds__(256) void ell_agg(const int* __restrict__ cnt,
                                               const int* __restrict__ ell,
                                               const ushort_t* __restrict__ xpb,
                                               const float* __restrict__ ssrc,
                                               const float* __restrict__ sdst,
                                               float* __restrict__ out,
                                               ushort_t* __restrict__ ohi,
                                               ushort_t* __restrict__ olo,
                                               int N, int mode)
{
    __shared__ int sidx[4][ELLW];
    int gid = blockIdx.x * blockDim.x + threadIdx.x;
    int d = gid >> 6;
    if (d >= N) return;
    int w = threadIdx.x >> 6;
    int lane = threadIdx.x & 63;
    int h = lane >> 3;
    float ssrc_h = ssrc[d * 8 + h];
    int end = cnt[d]; if (end > ELLW) end = ELLW;
    const int* row = ell + d * ELLW;
    // stage whole index row in LDS (one coalesced 256B load; clamp OOB slots)
    sidx[w][lane] = row[lane < end ? lane : 0];

    float den = 0.f, ax = 0.f, ay = 0.f, az = 0.f, aw = 0.f;
    for (int i = 0; i < end; i += 8) {
        int idx[8];
        #pragma unroll
        for (int j = 0; j < 8; j++) {
            int ii = i + j;
            idx[j] = sidx[w][ii < end ? ii : 0];
        }
        float t[8];
        #pragma unroll
        for (int j = 0; j < 8; j++) t[j] = sdst[idx[j] * 8 + h];
        ushort4 v[8];
        #pragma unroll
        for (int j = 0; j < 8; j++) v[j] = *(const ushort4*)(xpb + idx[j] * 256 + lane * 4);
        float w8[8];
        #pragma unroll
        for (int j = 0; j < 8; j++) {
            float al = ssrc_h + t[j];
            al = al > 0.f ? al : NEG_SLOPE * al;
            w8[j] = (i + j < end) ? __expf(al) : 0.f;
        }
        #pragma unroll
        for (int j = 0; j < 8; j++) {
            den += w8[j];
            ax += bf2f(v[j].x) * w8[j];
            ay += bf2f(v[j].y) * w8[j];
            az += bf2f(v[j].z) * w8[j];
            aw += bf2f(v[j].w) * w8[j];
        }
    }
    float inv = 1.f / den;
    ax *= inv; ay *= inv; az *= inv; aw *= inv;

    if (mode == 2) {
        #pragma unroll
        for (int m = 8; m <= 32; m <<= 1) {
            ax += __shfl_xor(ax, m);
            ay += __shfl_xor(ay, m);
            az += __shfl_xor(az, m);
            aw += __shfl_xor(aw, m);
        }
        if (lane < 8) {
            float4 r = { ax * 0.125f, ay * 0.125f, az * 0.125f, aw * 0.125f };
            *(float4*)(out + d * 32 + lane * 4) = r;
        }
        return;
    }
    ax = ax > 0.f ? ax : (__expf(ax) - 1.f);
    ay = ay > 0.f ? ay : (__expf(ay) - 1.f);
    az = az > 0.f ? az : (__expf(az) - 1.f);
    aw = aw > 0.f ? aw : (__expf(aw) - 1.f);
    ushort4 hs, ls;
    split_bf(ax, hs.x, ls.x);
    split_bf(ay, hs.y, ls.y);
    split_bf(az, hs.z, ls.z);
    split_bf(aw, hs.w, ls.w);
    *(ushort4*)(ohi + d * 256 + lane * 4) = hs;
    *(ushort4*)(olo + d * 256 + lane * 4) = ls;
}

extern "C" void kernel_launch(void* const* d_in, const int* in_sizes, int n_in,
                              void* d_out, int out_size, void* d_ws, size_t ws_size,
                              hipStream_t stream)
{
    const float* x  = (const float*)d_in[0];
    const int*   ei = (const int*)d_in[1];
    const float* W0 = (const float*)d_in[2];
    const float* A0 = (const float*)d_in[3];
    const float* B0 = (const float*)d_in[4];
    const float* att_s0 = (const float*)d_in[5];
    const float* att_d0 = (const float*)d_in[6];
    const float* As0 = (const float*)d_in[7];
    const float* Bs0 = (const float*)d_in[8];
    const float* Ad0 = (const float*)d_in[9];
    const float* Bd0 = (const float*)d_in[10];
    const float* W1 = (const float*)d_in[11];
    const float* A1 = (const float*)d_in[12];
    const float* B1 = (const float*)d_in[13];
    const float* att_s1 = (const float*)d_in[14];
    const float* att_d1 = (const float*)d_in[15];
    const float* As1 = (const float*)d_in[16];
    const float* Bs1 = (const float*)d_in[17];
    const float* Ad1 = (const float*)d_in[18];
    const float* Bd1 = (const float*)d_in[19];

    const int N = in_sizes[0] / 256;      // 10000
    const int E_real = in_sizes[1] / 2;   // 160000
    const int E_total = E_real + N;       // 170000

    // ---- workspace layout ----
    ushort_t* whi0 = (ushort_t*)d_ws;        // 65536 each
    ushort_t* wlo0 = whi0 + 65536;
    ushort_t* whi1 = wlo0 + 65536;
    ushort_t* wlo1 = whi1 + 65536;
    ushort_t* xhi  = wlo1 + 65536;           // N*256
    ushort_t* xlo  = xhi + 2560000;
    ushort_t* hbhi = xlo + 2560000;
    ushort_t* hblo = hbhi + 2560000;
    ushort_t* xpb  = hblo + 2560000;         // N*256 bf16 projected features
    float* effS0 = (float*)(xpb + 2560000);
    float* effD0 = effS0 + 256;
    float* effS1 = effD0 + 256;
    float* effD1 = effS1 + 256;
    float* ssrc  = effD1 + 256;              // N*8
    float* sdst  = ssrc + 80000;
    int* cnt = (int*)(sdst + 80000);         // N
    int* ell = cnt + 10016;                  // N*ELLW

    // ---- zero cnt, then fused prep (weights + x split + ELL fill) ----
    hipMemsetAsync(cnt, 0, (size_t)N * sizeof(int), stream);
    int convB = (N * 64 + 255) / 256;
    int fillB = (E_total + 255) / 256;
    prep_all<<<512 + convB + fillB, 256, 0, stream>>>(
        W0, A0, B0, att_s0, att_d0, As0, Bs0, Ad0, Bd0,
        W1, A1, B1, att_s1, att_d1, As1, Bs1, Ad1, Bd1,
        whi0, wlo0, whi1, wlo1, effS0, effD0, effS1, effD1,
        x, xhi, xlo, ei, E_real, E_total, cnt, ell, N);

    dim3 gg(4, (N + 63) / 64);
    int aggBlocks = (N * 64 + 255) / 256;

    // ---------------- layer 0 ----------------
    gemm_fused<<<gg, 256, 0, stream>>>(xhi, xlo, whi0, wlo0, effS0, effD0, xpb, ssrc, sdst, N);
    ell_agg<<<aggBlocks, 256, 0, stream>>>(cnt, ell, xpb, ssrc, sdst,
                                           nullptr, hbhi, hblo, N, 1);

    // ---------------- layer 1 ----------------
    gemm_fused<<<gg, 256, 0, stream>>>(hbhi, hblo, whi1, wlo1, effS1, effD1, xpb, ssrc, sdst, N);
    ell_agg<<<aggBlocks, 256, 0, stream>>>(cnt, ell, xpb, ssrc, sdst,
                                           (float*)d_out, nullptr, nullptr, N, 2);
}

// Round 10
// 175.114 us; speedup vs baseline: 7.7884x; 1.0185x over previous
//
#include <hip/hip_runtime.h>

#define LORA_SCALE 4.0f
#define ATT_SCALE 8.0f
#define NEG_SLOPE 0.2f
#define ELLW 64

typedef __attribute__((ext_vector_type(8))) short bf16x8;
typedef __attribute__((ext_vector_type(4))) float f32x4;
typedef unsigned short ushort_t;
typedef unsigned int uint_t;

__device__ inline ushort_t f2bf(float f) {
    uint_t u = __float_as_uint(f);
    u += 0x7fff + ((u >> 16) & 1);     // RNE
    return (ushort_t)(u >> 16);
}
__device__ inline float bf2f(ushort_t h) {
    return __uint_as_float(((uint_t)h) << 16);
}
__device__ inline void split_bf(float f, ushort_t& h, ushort_t& l) {
    h = f2bf(f);
    l = f2bf(f - bf2f(h));
}

// ---------- fused prep: weights(2 layers) + x->bf16 split + ELL fill ----------
// requires cnt[] zeroed beforehand (hipMemsetAsync)
__global__ void prep_all(const float* __restrict__ W0, const float* __restrict__ A0,
                         const float* __restrict__ B0,
                         const float* __restrict__ att_s0, const float* __restrict__ att_d0,
                         const float* __restrict__ As0, const float* __restrict__ Bs0,
                         const float* __restrict__ Ad0, const float* __restrict__ Bd0,
                         const float* __restrict__ W1, const float* __restrict__ A1,
                         const float* __restrict__ B1,
                         const float* __restrict__ att_s1, const float* __restrict__ att_d1,
                         const float* __restrict__ As1, const float* __restrict__ Bs1,
                         const float* __restrict__ Ad1, const float* __restrict__ Bd1,
                         ushort_t* __restrict__ whi0, ushort_t* __restrict__ wlo0,
                         ushort_t* __restrict__ whi1, ushort_t* __restrict__ wlo1,
                         float* __restrict__ effS0, float* __restrict__ effD0,
                         float* __restrict__ effS1, float* __restrict__ effD1,
                         const float* __restrict__ x, ushort_t* __restrict__ xhi,
                         ushort_t* __restrict__ xlo,
                         const int* __restrict__ ei, int E_real, int E_total,
                         int* __restrict__ cnt, int* __restrict__ ell, int N)
{
    int b = blockIdx.x;
    int t = threadIdx.x;
    if (b < 512) {
        int layer = b >> 8;
        int i = (b & 255) * 256 + t;
        const float* W = layer ? W1 : W0;
        const float* A = layer ? A1 : A0;
        const float* B = layer ? B1 : B0;
        int r = i >> 8, c = i & 255;
        float acc = W[i];
        #pragma unroll
        for (int k = 0; k < 8; k++) acc += LORA_SCALE * B[r * 8 + k] * A[k * 256 + c];
        ushort_t h, l;
        split_bf(acc, h, l);
        if (layer) { whi1[i] = h; wlo1[i] = l; }
        else       { whi0[i] = h; wlo0[i] = l; }
        if (i < 256) {
            int c2 = i & 31;
            const float* as_ = layer ? att_s1 : att_s0;
            const float* ad_ = layer ? att_d1 : att_d0;
            const float* As = layer ? As1 : As0;
            const float* Bs = layer ? Bs1 : Bs0;
            const float* Ad = layer ? Ad1 : Ad0;
            const float* Bd = layer ? Bd1 : Bd0;
            float es = as_[i], ed = ad_[i];
            #pragma unroll
            for (int k = 0; k < 4; k++) {
                es += ATT_SCALE * Bs[k] * As[k * 32 + c2];
                ed += ATT_SCALE * Bd[k] * Ad[k * 32 + c2];
            }
            if (layer) { effS1[i] = es; effD1[i] = ed; }
            else       { effS0[i] = es; effD0[i] = ed; }
        }
        return;
    }
    int cb = b - 512;
    int convB = (N * 32 + 255) / 256;     // 8 floats per thread
    if (cb < convB) {
        int i = cb * 256 + t;
        if (i >= N * 32) return;
        float4 v0 = *(const float4*)(x + i * 8);
        float4 v1 = *(const float4*)(x + i * 8 + 4);
        ushort4 h0, l0, h1, l1;
        split_bf(v0.x, h0.x, l0.x);
        split_bf(v0.y, h0.y, l0.y);
        split_bf(v0.z, h0.z, l0.z);
        split_bf(v0.w, h0.w, l0.w);
        split_bf(v1.x, h1.x, l1.x);
        split_bf(v1.y, h1.y, l1.y);
        split_bf(v1.z, h1.z, l1.z);
        split_bf(v1.w, h1.w, l1.w);
        *(ushort4*)(xhi + i * 8) = h0;
        *(ushort4*)(xhi + i * 8 + 4) = h1;
        *(ushort4*)(xlo + i * 8) = l0;
        *(ushort4*)(xlo + i * 8 + 4) = l1;
        return;
    }
    // ---- ELL fill ----
    int e = (cb - convB) * 256 + t;
    if (e >= E_total) return;
    int s, d;
    if (e < E_real) { s = ei[e]; d = ei[E_real + e]; }
    else            { s = d = e - E_real; }
    int pos = atomicAdd(&cnt[d], 1);
    if (pos < ELLW) ell[d * ELLW + pos] = s;
}

// ---------- MFMA GEMM + fused attention scores; B-tile staged in LDS ----------
// block = 512 threads = 8 waves sharing one 64-col n-tile; wave w owns rows
// m0 = by*128 + w*16. B staged in MFMA-fragment order -> conflict-free ds_read_b128.
// grid = (4, ceil(M/128))
__global__ __launch_bounds__(512) void gemm_fused(
    const ushort_t* __restrict__ Ahi, const ushort_t* __restrict__ Alo,
    const ushort_t* __restrict__ Bhi, const ushort_t* __restrict__ Blo,
    const float* __restrict__ effS, const float* __restrict__ effD,
    ushort_t* __restrict__ Cb, float* __restrict__ ssrc, float* __restrict__ sdst, int M)
{
    __shared__ ushort_t sBh[16384];   // 32 KB: hi fragments
    __shared__ ushort_t sBl[16384];   // 32 KB: lo fragments
    const int K = 256;
    int tid = threadIdx.x;
    int n0 = blockIdx.x * 64;

    // ---- stage B-tile (64 rows x 256 K, hi+lo) into fragment-ordered LDS ----
    // fragment addr for (row rr, k): t=rr>>4, l16=rr&15, kblk=k>>5, quad=(k>>3)&3
    //   dst = (((t*8 + kblk)*4 + quad)*16 + l16)*8
    const ushort_t* srcH = Bhi + (size_t)n0 * K;
    const ushort_t* srcL = Blo + (size_t)n0 * K;
    #pragma unroll
    for (int c = 0; c < 4; c++) {
        int g  = c * 512 + tid;        // chunk id 0..2047 (8 shorts each)
        int rr = g >> 5;               // row 0..63
        int ch = g & 31;               // 8-short chunk within row
        int kblk = ch >> 2, quad = ch & 3;
        int tt = rr >> 4, l16r = rr & 15;
        int dst = (((tt * 8 + kblk) * 4 + quad) * 16 + l16r) * 8;
        *(bf16x8*)&sBh[dst] = *(const bf16x8*)(srcH + rr * K + ch * 8);
        *(bf16x8*)&sBl[dst] = *(const bf16x8*)(srcL + rr * K + ch * 8);
    }
    __syncthreads();

    int w = tid >> 6;
    int lane = tid & 63;
    int quad = lane >> 4;
    int l16 = lane & 15;
    int m0 = blockIdx.y * 128 + w * 16;
    int mr = m0 + l16; if (mr >= M) mr = M - 1;

    const ushort_t* ah = Ahi + mr * K + quad * 8;
    const ushort_t* al = Alo + mr * K + quad * 8;

    f32x4 acc[4] = {};
    #pragma unroll
    for (int kb = 0; kb < 8; kb++) {
        bf16x8 a_hi = *(const bf16x8*)(ah + kb * 32);
        bf16x8 a_lo = *(const bf16x8*)(al + kb * 32);
        #pragma unroll
        for (int t = 0; t < 4; t++) {
            int off = (((t * 8 + kb) * 4 + quad) * 16 + l16) * 8;
            bf16x8 b_hi = *(const bf16x8*)&sBh[off];
            bf16x8 b_lo = *(const bf16x8*)&sBl[off];
            acc[t] = __builtin_amdgcn_mfma_f32_16x16x32_bf16(a_hi, b_hi, acc[t], 0, 0, 0);
            acc[t] = __builtin_amdgcn_mfma_f32_16x16x32_bf16(a_hi, b_lo, acc[t], 0, 0, 0);
            acc[t] = __builtin_amdgcn_mfma_f32_16x16x32_bf16(a_lo, b_hi, acc[t], 0, 0, 0);
        }
    }

    // ---- store C as bf16: C/D layout col = l16, row = quad*4 + reg ----
    #pragma unroll
    for (int t = 0; t < 4; t++) {
        #pragma unroll
        for (int r = 0; r < 4; r++) {
            int m = m0 + quad * 4 + r;
            if (m < M) Cb[m * 256 + n0 + t * 16 + l16] = f2bf(acc[t][r]);
        }
    }

    // ---- fused scores (fp32, from accumulators) ----
    int h0 = n0 >> 5;
    float vs[2][4], vd[2][4];
    #pragma unroll
    for (int g = 0; g < 2; g++) {
        float e0s = effS[n0 + 32 * g + l16];
        float e1s = effS[n0 + 32 * g + 16 + l16];
        float e0d = effD[n0 + 32 * g + l16];
        float e1d = effD[n0 + 32 * g + 16 + l16];
        #pragma unroll
        for (int r = 0; r < 4; r++) {
            vs[g][r] = acc[2 * g][r] * e0s + acc[2 * g + 1][r] * e1s;
            vd[g][r] = acc[2 * g][r] * e0d + acc[2 * g + 1][r] * e1d;
        }
    }
    #pragma unroll
    for (int m = 1; m <= 8; m <<= 1) {
        #pragma unroll
        for (int g = 0; g < 2; g++)
            #pragma unroll
            for (int r = 0; r < 4; r++) {
                vs[g][r] += __shfl_xor(vs[g][r], m);
                vd[g][r] += __shfl_xor(vd[g][r], m);
            }
    }
    if (l16 == 0) {
        #pragma unroll
        for (int g = 0; g < 2; g++)
            #pragma unroll
            for (int r = 0; r < 4; r++) {
                int m = m0 + quad * 4 + r;
                if (m < M) {
                    ssrc[m * 8 + h0 + g] = vs[g][r];
                    sdst[m * 8 + h0 + g] = vd[g][r];
                }
            }
    }
}

// ---------- gather-aggregate over ELL: LDS-staged indices, unroll-8 ----------
// one wave per node. mode 1: ELU -> bf16 hi/lo 256ch; mode 2: head-mean -> 32ch fp32
__global__ __launch_bounds__(256) void ell_agg(const int* __restrict__ cnt,
                                               const int* __restrict__ ell,
                                               const ushort_t* __restrict__ xpb,
                                               const float* __restrict__ ssrc,
                                               const float* __restrict__ sdst,
                                               float* __restrict__ out,
                                               ushort_t* __restrict__ ohi,
                                               ushort_t* __restrict__ olo,
                                               int N, int mode)
{
    __shared__ int sidx[4][ELLW];
    int gid = blockIdx.x * blockDim.x + threadIdx.x;
    int d = gid >> 6;
    if (d >= N) return;
    int w = threadIdx.x >> 6;
    int lane = threadIdx.x & 63;
    int h = lane >> 3;
    float ssrc_h = ssrc[d * 8 + h];
    int end = cnt[d]; if (end > ELLW) end = ELLW;
    const int* row = ell + d * ELLW;
    // stage whole index row in LDS (one coalesced 256B load; clamp OOB slots)
    sidx[w][lane] = row[lane < end ? lane : 0];

    float den = 0.f, ax = 0.f, ay = 0.f, az = 0.f, aw = 0.f;
    for (int i = 0; i < end; i += 8) {
        int idx[8];
        #pragma unroll
        for (int j = 0; j < 8; j++) {
            int ii = i + j;
            idx[j] = sidx[w][ii < end ? ii : 0];
        }
        float t[8];
        #pragma unroll
        for (int j = 0; j < 8; j++) t[j] = sdst[idx[j] * 8 + h];
        ushort4 v[8];
        #pragma unroll
        for (int j = 0; j < 8; j++) v[j] = *(const ushort4*)(xpb + idx[j] * 256 + lane * 4);
        float w8[8];
        #pragma unroll
        for (int j = 0; j < 8; j++) {
            float al = ssrc_h + t[j];
            al = al > 0.f ? al : NEG_SLOPE * al;
            w8[j] = (i + j < end) ? __expf(al) : 0.f;
        }
        #pragma unroll
        for (int j = 0; j < 8; j++) {
            den += w8[j];
            ax += bf2f(v[j].x) * w8[j];
            ay += bf2f(v[j].y) * w8[j];
            az += bf2f(v[j].z) * w8[j];
            aw += bf2f(v[j].w) * w8[j];
        }
    }
    float inv = 1.f / den;
    ax *= inv; ay *= inv; az *= inv; aw *= inv;

    if (mode == 2) {
        #pragma unroll
        for (int m = 8; m <= 32; m <<= 1) {
            ax += __shfl_xor(ax, m);
            ay += __shfl_xor(ay, m);
            az += __shfl_xor(az, m);
            aw += __shfl_xor(aw, m);
        }
        if (lane < 8) {
            float4 r = { ax * 0.125f, ay * 0.125f, az * 0.125f, aw * 0.125f };
            *(float4*)(out + d * 32 + lane * 4) = r;
        }
        return;
    }
    ax = ax > 0.f ? ax : (__expf(ax) - 1.f);
    ay = ay > 0.f ? ay : (__expf(ay) - 1.f);
    az = az > 0.f ? az : (__expf(az) - 1.f);
    aw = aw > 0.f ? aw : (__expf(aw) - 1.f);
    ushort4 hs, ls;
    split_bf(ax, hs.x, ls.x);
    split_bf(ay, hs.y, ls.y);
    split_bf(az, hs.z, ls.z);
    split_bf(aw, hs.w, ls.w);
    *(ushort4*)(ohi + d * 256 + lane * 4) = hs;
    *(ushort4*)(olo + d * 256 + lane * 4) = ls;
}

extern "C" void kernel_launch(void* const* d_in, const int* in_sizes, int n_in,
                              void* d_out, int out_size, void* d_ws, size_t ws_size,
                              hipStream_t stream)
{
    const float* x  = (const float*)d_in[0];
    const int*   ei = (const int*)d_in[1];
    const float* W0 = (const float*)d_in[2];
    const float* A0 = (const float*)d_in[3];
    const float* B0 = (const float*)d_in[4];
    const float* att_s0 = (const float*)d_in[5];
    const float* att_d0 = (const float*)d_in[6];
    const float* As0 = (const float*)d_in[7];
    const float* Bs0 = (const float*)d_in[8];
    const float* Ad0 = (const float*)d_in[9];
    const float* Bd0 = (const float*)d_in[10];
    const float* W1 = (const float*)d_in[11];
    const float* A1 = (const float*)d_in[12];
    const float* B1 = (const float*)d_in[13];
    const float* att_s1 = (const float*)d_in[14];
    const float* att_d1 = (const float*)d_in[15];
    const float* As1 = (const float*)d_in[16];
    const float* Bs1 = (const float*)d_in[17];
    const float* Ad1 = (const float*)d_in[18];
    const float* Bd1 = (const float*)d_in[19];

    const int N = in_sizes[0] / 256;      // 10000
    const int E_real = in_sizes[1] / 2;   // 160000
    const int E_total = E_real + N;       // 170000

    // ---- workspace layout ----
    ushort_t* whi0 = (ushort_t*)d_ws;        // 65536 each
    ushort_t* wlo0 = whi0 + 65536;
    ushort_t* whi1 = wlo0 + 65536;
    ushort_t* wlo1 = whi1 + 65536;
    ushort_t* xhi  = wlo1 + 65536;           // N*256
    ushort_t* xlo  = xhi + 2560000;
    ushort_t* hbhi = xlo + 2560000;
    ushort_t* hblo = hbhi + 2560000;
    ushort_t* xpb  = hblo + 2560000;         // N*256 bf16 projected features
    float* effS0 = (float*)(xpb + 2560000);
    float* effD0 = effS0 + 256;
    float* effS1 = effD0 + 256;
    float* effD1 = effS1 + 256;
    float* ssrc  = effD1 + 256;              // N*8
    float* sdst  = ssrc + 80000;
    int* cnt = (int*)(sdst + 80000);         // N
    int* ell = cnt + 10016;                  // N*ELLW

    // ---- zero cnt, then fused prep (weights + x split + ELL fill) ----
    hipMemsetAsync(cnt, 0, (size_t)N * sizeof(int), stream);
    int convB = (N * 32 + 255) / 256;
    int fillB = (E_total + 255) / 256;
    prep_all<<<512 + convB + fillB, 256, 0, stream>>>(
        W0, A0, B0, att_s0, att_d0, As0, Bs0, Ad0, Bd0,
        W1, A1, B1, att_s1, att_d1, As1, Bs1, Ad1, Bd1,
        whi0, wlo0, whi1, wlo1, effS0, effD0, effS1, effD1,
        x, xhi, xlo, ei, E_real, E_total, cnt, ell, N);

    dim3 gg(4, (N + 127) / 128);
    int aggBlocks = (N * 64 + 255) / 256;

    // ---------------- layer 0 ----------------
    gemm_fused<<<gg, 512, 0, stream>>>(xhi, xlo, whi0, wlo0, effS0, effD0, xpb, ssrc, sdst, N);
    ell_agg<<<aggBlocks, 256, 0, stream>>>(cnt, ell, xpb, ssrc, sdst,
                                           nullptr, hbhi, hblo, N, 1);

    // ---------------- layer 1 ----------------
    gemm_fused<<<gg, 512, 0, stream>>>(hbhi, hblo, whi1, wlo1, effS1, effD1, xpb, ssrc, sdst, N);
    ell_agg<<<aggBlocks, 256, 0, stream>>>(cnt, ell, xpb, ssrc, sdst,
                                           (float*)d_out, nullptr, nullptr, N, 2);
}